// Round 1
// 256.721 us; speedup vs baseline: 1.0174x; 1.0174x over previous
//
#include <hip/hip_runtime.h>
#include <hip/hip_bf16.h>

typedef __attribute__((ext_vector_type(8))) short short8;
typedef __attribute__((ext_vector_type(4))) float floatx4;

#define CAP 8192          // per-bucket edge pool capacity
#define BIN_CH 2048       // edges binned per block

// ---------------- runtime dtype helpers ----------------
__device__ __forceinline__ float read_f(const void* p, long long i, int fp32m) {
  return fp32m ? ((const float*)p)[i] : (float)((const __hip_bfloat16*)p)[i];
}
__device__ __forceinline__ float bf2f(unsigned short u) {
  return __uint_as_float((unsigned)u << 16);
}
__device__ __forceinline__ unsigned short f2bf(float f) {   // RNE
  const unsigned u = __float_as_uint(f);
  return (unsigned short)((u + 0x7fffu + ((u >> 16) & 1u)) >> 16);
}

// ---------------- fused prep kernel ----------------
__device__ __forceinline__ void pack_one(const void* W, unsigned short* Wp, int i,
                                         int K, int NOUT, int m) {
  const int k = i / NOUT, n = i - k * NOUT;
  const int ct = n >> 4, c = n & 15, ks = k >> 5, quad = (k >> 3) & 3, j = k & 7;
  Wp[(((ct * (K / 32) + ks) * 4 + quad) * 16 + c) * 8 + j] = f2bf(read_f(W, i, m));
}

__global__ __launch_bounds__(256) void prep_k(const void* __restrict__ x,
                                              const void* __restrict__ ei,
                                              const void* __restrict__ W1,
                                              const void* __restrict__ a1s,
                                              const void* __restrict__ a1d,
                                              const void* __restrict__ b1,
                                              const void* __restrict__ W2,
                                              const void* __restrict__ a2s,
                                              const void* __restrict__ a2d,
                                              const void* __restrict__ b2,
                                              unsigned short* __restrict__ Wp1,
                                              unsigned short* __restrict__ Wp2,
                                              float* __restrict__ w_as1, float* __restrict__ w_ad1,
                                              float* __restrict__ v_a2s, float* __restrict__ v_a2d,
                                              float* __restrict__ v_b1,  float* __restrict__ v_b2,
                                              int* __restrict__ bkcnt,
                                              int* __restrict__ flags) {
  __shared__ int fl_s[2];
  const int t = threadIdx.x, b = blockIdx.x;
  if (t < 64) {
    const unsigned short w = ((const unsigned short*)x)[t * 2];
    const int ef = (w >> 7) & 0xff;
    const bool bf_ok = (ef >= 90 && ef <= 140);
    const unsigned hi = ((const unsigned*)ei)[t * 2 + 1];
    const unsigned long long bm = __ballot(bf_ok);
    const unsigned long long zm = __ballot(hi == 0u);
    if (t == 0) {
      fl_s[0] = (bm == ~0ull) ? 0 : 1;   // fp32 mode
      fl_s[1] = (zm == ~0ull) ? 1 : 0;   // int64 mode
      if (b == 0) { flags[0] = fl_s[0]; flags[1] = fl_s[1]; }
    }
  }
  __syncthreads();
  const int m = fl_s[0];

  if (b < 128) {
    pack_one(W1, Wp1, b * 256 + t, 128, 256, m);
  } else if (b < 256) {
    pack_one(W2, Wp2, (b - 128) * 256 + t, 256, 128, m);
  } else if (b == 256) {
    if (t < 128) {
      float sa = 0.f, sb = 0.f;
      for (int j = 0; j < 256; ++j) {
        const float w = read_f(W1, (long long)t * 256 + j, m);
        sa = fmaf(w, read_f(a1s, j, m), sa);
        sb = fmaf(w, read_f(a1d, j, m), sb);
      }
      w_as1[t] = sa;
      w_ad1[t] = sb;
    }
  } else if (b == 257) {
    if (t < 128) v_a2s[t] = read_f(a2s, t, m);
    else         v_a2d[t - 128] = read_f(a2d, t - 128, m);
  } else if (b == 258) {
    v_b1[t] = read_f(b1, t, m);
  } else {
    if (t < 128) v_b2[t] = read_f(b2, t, m);
    bkcnt[t] = 0;
  }
}

// ---------------- canon x -> bf16 + fused alpha1 (wave per node) ----------------
__global__ __launch_bounds__(256) void canon_alpha_k(const void* __restrict__ x,
                                                     const float* __restrict__ was,
                                                     const float* __restrict__ wad,
                                                     unsigned short* __restrict__ xb,
                                                     float* __restrict__ as_, float* __restrict__ ad_,
                                                     int n, const int* __restrict__ flags) {
  const int gid = blockIdx.x * 256 + threadIdx.x;
  const int node = gid >> 6, lane = gid & 63;
  if (node >= n) return;
  const int m = flags[0];
  const long long base = (long long)node * 128 + lane * 2;
  const float v0 = read_f(x, base, m), v1 = read_f(x, base + 1, m);
  ushort2 q;
  q.x = f2bf(v0); q.y = f2bf(v1);
  *(ushort2*)(xb + base) = q;
  float s1 = fmaf(v0, was[lane * 2], v1 * was[lane * 2 + 1]);
  float s2 = fmaf(v0, wad[lane * 2], v1 * wad[lane * 2 + 1]);
  for (int off = 32; off; off >>= 1) {
    s1 += __shfl_down(s1, off);
    s2 += __shfl_down(s2, off);
  }
  if (lane == 0) { as_[node] = s1; ad_[node] = s2; }
}

// ---------------- edge decode ----------------
__device__ __forceinline__ void edge_sd(const void* ei, int e, int E, int i64m, int n,
                                        int& s, int& d) {
  if (e < E) {
    if (i64m) { s = (int)((const long long*)ei)[e]; d = (int)((const long long*)ei)[E + e]; }
    else      { s = ((const int*)ei)[e];            d = ((const int*)ei)[E + e]; }
  } else { s = d = e - E; }  // self loop
  s = min(max(s, 0), n - 1);
  d = min(max(d, 0), n - 1);
}

// ---------------- bucketed CSR build ----------------
__global__ __launch_bounds__(256) void bin_k(const void* __restrict__ ei,
                                             unsigned* __restrict__ bpool,
                                             int* __restrict__ bkcnt,
                                             int E, int EN, int n,
                                             const int* __restrict__ flags) {
  __shared__ unsigned stage[BIN_CH];
  __shared__ unsigned daddr[BIN_CH];
  __shared__ int bcnt_s[256], boff_s[256], gbase_s[256], sd[256];
  __shared__ int vtot_s;
  const int t = threadIdx.x;
  const int c0 = blockIdx.x * BIN_CH;
  const int i64m = flags[1];
  bcnt_s[t] = 0;
  __syncthreads();

  unsigned val[BIN_CH / 256];
  int buk[BIN_CH / 256];
#pragma unroll
  for (int i = 0; i < BIN_CH / 256; ++i) {
    const int e = c0 + i * 256 + t;
    if (e < EN) {
      int s, d;
      edge_sd(ei, e, E, i64m, n, s, d);
      buk[i] = d >> 8;
      val[i] = (unsigned)s | ((unsigned)(d & 255) << 16);
      atomicAdd(&bcnt_s[buk[i]], 1);
    } else buk[i] = -1;
  }
  __syncthreads();

  const int c = bcnt_s[t];
  sd[t] = c;
  __syncthreads();
  for (int off = 1; off < 256; off <<= 1) {
    const int v = (t >= off) ? sd[t - off] : 0;
    __syncthreads();
    sd[t] += v;
    __syncthreads();
  }
  boff_s[t] = sd[t] - c;
  if (t == 255) vtot_s = sd[255];
  gbase_s[t] = (c > 0) ? atomicAdd(&bkcnt[t], c) : 0;
  bcnt_s[t] = 0;   // becomes cursor
  __syncthreads();

#pragma unroll
  for (int i = 0; i < BIN_CH / 256; ++i) {
    if (buk[i] >= 0) {
      const int lp = atomicAdd(&bcnt_s[buk[i]], 1);
      const int si = boff_s[buk[i]] + lp;
      stage[si] = val[i];
      const int gp = gbase_s[buk[i]] + lp;
      daddr[si] = (gp < CAP) ? (unsigned)(buk[i] * CAP + gp) : 0xFFFFFFFFu;
    }
  }
  __syncthreads();

  const int vt = vtot_s;
  for (int idx = t; idx < vt; idx += 256)
    if (daddr[idx] != 0xFFFFFFFFu) bpool[daddr[idx]] = stage[idx];
}

__global__ __launch_bounds__(256) void bucket_csr_k(const unsigned* __restrict__ bpool,
                                                    const int* __restrict__ bkcnt,
                                                    unsigned short* __restrict__ csrc,
                                                    int* __restrict__ start_g,
                                                    int* __restrict__ deg_g, int n) {
  __shared__ int deg_s[256], cur_s[256], sd[256];
  const int t = threadIdx.x, b = blockIdx.x;
  int cnt = bkcnt[b];
  if (cnt > CAP) cnt = CAP;
  deg_s[t] = 0;
  __syncthreads();
  for (int idx = t; idx < cnt; idx += 256) {
    const unsigned v = bpool[b * CAP + idx];
    atomicAdd(&deg_s[(v >> 16) & 255], 1);
  }
  __syncthreads();
  const int dg = deg_s[t];
  sd[t] = dg;
  __syncthreads();
  for (int off = 1; off < 256; off <<= 1) {
    const int v = (t >= off) ? sd[t - off] : 0;
    __syncthreads();
    sd[t] += v;
    __syncthreads();
  }
  const int excl = sd[t] - dg;
  const int node = b * 256 + t;
  if (node < n) { start_g[node] = b * CAP + excl; deg_g[node] = dg; }
  cur_s[t] = excl;
  __syncthreads();
  for (int idx = t; idx < cnt; idx += 256) {
    const unsigned v = bpool[b * CAP + idx];
    const int p = atomicAdd(&cur_s[(v >> 16) & 255], 1);
    csrc[b * CAP + p] = (unsigned short)(v & 0xFFFFu);
  }
}

// ---------------- agg primitive (wave-per-node, F=128, 4 edge-slots x 16 col-slots) ----
__device__ __forceinline__ void agg_node(const int start, const int end,
                                         const unsigned short* __restrict__ csrc,
                                         const float* __restrict__ as_, const float adv,
                                         const unsigned short* __restrict__ xw,
                                         const int lane, float* acc) {
  const int slot = lane >> 4, col = lane & 15;
  float dsum = 0.f;
#pragma unroll
  for (int c = 0; c < 8; ++c) acc[c] = 0.f;

  for (int base = start; base < end; base += 64) {
    const int idx = base + lane;
    int s_pre = 0;
    float w_pre = 0.f;
    if (idx < end) {
      s_pre = (int)csrc[idx];
      float v = as_[s_pre] + adv;
      v = (v >= 0.f) ? v : 0.2f * v;
      w_pre = __expf(fminf(v, 60.f));
    }
    dsum += w_pre;
    const int cnt = min(64, end - base);
    for (int j = 0; j < cnt; j += 8) {
      const int jj0 = j + slot, jj1 = j + 4 + slot;
      int s0 = __shfl(s_pre, jj0);
      float w0 = __shfl(w_pre, jj0);
      int s1 = __shfl(s_pre, jj1);
      float w1 = __shfl(w_pre, jj1);
      const bool ok0 = (jj0 < cnt), ok1 = (jj1 < cnt);
      s0 = ok0 ? s0 : 0; w0 = ok0 ? w0 : 0.f;
      s1 = ok1 ? s1 : 0; w1 = ok1 ? w1 : 0.f;
      const short8 q0 = *(const short8*)(xw + (size_t)s0 * 128 + col * 8);
      const short8 q1 = *(const short8*)(xw + (size_t)s1 * 128 + col * 8);
#pragma unroll
      for (int c = 0; c < 8; ++c) {
        acc[c] = fmaf(w0, bf2f((unsigned short)q0[c]), acc[c]);
        acc[c] = fmaf(w1, bf2f((unsigned short)q1[c]), acc[c]);
      }
    }
  }
  for (int off = 32; off; off >>= 1) dsum += __shfl_down(dsum, off);
  dsum = __shfl(dsum, 0);
  const float r = 1.f / fmaxf(dsum, 1e-30f);
#pragma unroll
  for (int c = 0; c < 8; ++c) {
    acc[c] += __shfl_xor(acc[c], 16);
    acc[c] += __shfl_xor(acc[c], 32);
    acc[c] *= r;
  }
}

// ---------------- FUSED layer-1+2 GEMMs: agg(x) -> LDS -> GEMM1 -> relu -> LDS -> GEMM2
//                  -> xw2 (bf16) + alpha2 ----------------------------------------------
// 1024 threads = 16 waves; block handles 16 nodes. Phase 1: wave w aggs node base+w into
// LDS row w (stride LSTR=136 shorts). Phase 2 (GEMM1): wave w computes H cols w*16..+16
// for the 16 rows, relu(+b1), stages bf16 into hs (stride HSTR=264 shorts -> 2-way-free
// bank pattern for the b128 column reads). Phase 3 (GEMM2): waves 0..7 compute xw2
// col-tile w (8 MFMAs each, K=256) + alpha2 partials (shfl_xor over cols, LDS-atomic
// over col-tiles). H never touches HBM; gemm_mfma_k kernel eliminated.
#define LSTR 136
#define HSTR 264
__global__ __launch_bounds__(1024) void agg_gemm12_k(const int* __restrict__ start_g,
                                                     const int* __restrict__ deg_g,
                                                     const unsigned short* __restrict__ csrc,
                                                     const float* __restrict__ as_,
                                                     const float* __restrict__ ad_,
                                                     const unsigned short* __restrict__ xb,
                                                     const unsigned short* __restrict__ Wp1,
                                                     const unsigned short* __restrict__ Wp2,
                                                     const float* __restrict__ v_b1,
                                                     const float* __restrict__ v_a2s,
                                                     const float* __restrict__ v_a2d,
                                                     unsigned short* __restrict__ xw2,
                                                     float* __restrict__ as2,
                                                     float* __restrict__ ad2, int n) {
  __shared__ unsigned short lds[16 * LSTR];
  __shared__ unsigned short hs[16 * HSTR];
  __shared__ float al_s[16], al_d[16];
  const int wv = threadIdx.x >> 6, lane = threadIdx.x & 63;
  const int slot = lane >> 4, col = lane & 15;
  const int node = blockIdx.x * 16 + wv;

  float acc[8];
  if (node < n) {
    const int start = start_g[node];
    agg_node(start, start + deg_g[node], csrc, as_, ad_[node], xb, lane, acc);
  } else {
#pragma unroll
    for (int c = 0; c < 8; ++c) acc[c] = 0.f;
  }
  if (slot == 0) {
    short8 q;
#pragma unroll
    for (int c = 0; c < 8; ++c) q[c] = (short)f2bf(acc[c]);
    *(short8*)&lds[wv * LSTR + col * 8] = q;
  }
  __syncthreads();

  // ---- GEMM1: wave wv = col-tile ct of H; A from lds, B = Wp1, K=128 (KS=4) ----
  const int quad = slot, c = col;
  floatx4 g = {0.f, 0.f, 0.f, 0.f};
#pragma unroll
  for (int ks = 0; ks < 4; ++ks) {
    const short8 af = *(const short8*)&lds[c * LSTR + ks * 32 + quad * 8];
    const short8 bf = *(const short8*)(Wp1 + (size_t)((wv * 4 + ks) * 64 + lane) * 8);
    g = __builtin_amdgcn_mfma_f32_16x16x32_bf16(af, bf, g, 0, 0, 0);
  }
  const float bv = v_b1[wv * 16 + c];
#pragma unroll
  for (int r = 0; r < 4; ++r) {
    const float v = g[r] + bv;
    hs[(quad * 4 + r) * HSTR + wv * 16 + c] = f2bf(v > 0.f ? v : 0.f);
  }
  if (threadIdx.x < 16) { al_s[threadIdx.x] = 0.f; al_d[threadIdx.x] = 0.f; }
  __syncthreads();

  // ---- GEMM2: waves 0..7 = col-tile ct of xw2; A from hs, B = Wp2, K=256 (KS=8) ----
  const int row0 = blockIdx.x * 16;
  if (wv < 8) {
    floatx4 a2 = {0.f, 0.f, 0.f, 0.f};
#pragma unroll
    for (int ks = 0; ks < 8; ++ks) {
      const short8 af = *(const short8*)&hs[c * HSTR + ks * 32 + quad * 8];
      const short8 bf = *(const short8*)(Wp2 + (size_t)((wv * 8 + ks) * 64 + lane) * 8);
      a2 = __builtin_amdgcn_mfma_f32_16x16x32_bf16(af, bf, a2, 0, 0, 0);
    }
    const float asv = v_a2s[wv * 16 + c], adv = v_a2d[wv * 16 + c];
    float pa_s[4], pa_d[4];
#pragma unroll
    for (int r = 0; r < 4; ++r) {
      pa_s[r] = a2[r] * asv;
      pa_d[r] = a2[r] * adv;
      const int rr = row0 + quad * 4 + r;
      if (rr < n) xw2[(size_t)rr * 128 + wv * 16 + c] = f2bf(a2[r]);
    }
    for (int off = 1; off < 16; off <<= 1) {
#pragma unroll
      for (int r = 0; r < 4; ++r) {
        pa_s[r] += __shfl_xor(pa_s[r], off);
        pa_d[r] += __shfl_xor(pa_d[r], off);
      }
    }
    if (c == 0) {
#pragma unroll
      for (int r = 0; r < 4; ++r) {
        atomicAdd(&al_s[quad * 4 + r], pa_s[r]);
        atomicAdd(&al_d[quad * 4 + r], pa_d[r]);
      }
    }
  }
  __syncthreads();
  if (threadIdx.x < 16) {
    const int rr = row0 + threadIdx.x;
    if (rr < n) { as2[rr] = al_s[threadIdx.x]; ad2[rr] = al_d[threadIdx.x]; }
  }
}

// ---------------- final aggregation: out = acc/dsum + b2, dtype per flags[0] ----------------
__global__ __launch_bounds__(256) void agg_out_k(const int* __restrict__ start_g,
                                                 const int* __restrict__ deg_g,
                                                 const unsigned short* __restrict__ csrc,
                                                 const float* __restrict__ as_,
                                                 const float* __restrict__ ad_,
                                                 const unsigned short* __restrict__ xw,
                                                 const float* __restrict__ bias,
                                                 void* __restrict__ outp, int n,
                                                 const int* __restrict__ flags) {
  const int gid = blockIdx.x * 256 + threadIdx.x;
  const int node = gid >> 6, lane = gid & 63;
  if (node >= n) return;
  const int slot = lane >> 4, col = lane & 15;
  const int start = start_g[node];
  float acc[8];
  agg_node(start, start + deg_g[node], csrc, as_, ad_[node], xw, lane, acc);
  if (slot == 0) {
    const int c0 = col * 8;
    if (flags[0]) {
      float* o = (float*)outp + (size_t)node * 128 + c0;
      floatx4 q0, q1;
#pragma unroll
      for (int c = 0; c < 4; ++c) {
        q0[c] = acc[c] + bias[c0 + c];
        q1[c] = acc[c + 4] + bias[c0 + 4 + c];
      }
      *(floatx4*)o = q0;
      *(floatx4*)(o + 4) = q1;
    } else {
      short8 q;
#pragma unroll
      for (int c = 0; c < 8; ++c) q[c] = (short)f2bf(acc[c] + bias[c0 + c]);
      *(short8*)((unsigned short*)outp + (size_t)node * 128 + c0) = q;
    }
  }
}

extern "C" void kernel_launch(void* const* d_in, const int* in_sizes, int n_in,
                              void* d_out, int out_size, void* d_ws, size_t ws_size,
                              hipStream_t stream) {
  const void* x   = d_in[0];
  const void* ei  = d_in[1];
  const void* W1  = d_in[2];
  const void* a1s = d_in[3];
  const void* a1d = d_in[4];
  const void* b1  = d_in[5];
  const void* W2  = d_in[6];
  const void* a2s = d_in[7];
  const void* a2d = d_in[8];
  const void* b2  = d_in[9];

  const int N  = in_sizes[0] / 128;   // 50000
  const int E  = in_sizes[1] / 2;     // 800000
  const int EN = E + N;
  const int NBUK = (N + 255) / 256;   // 196 buckets

  // ---- workspace layout ----
  unsigned short* B1 = (unsigned short*)d_ws;               // N*128 bf16: x_bf16
  unsigned short* H  = B1 + (size_t)N * 128;                // N*256 bf16 region:
  unsigned short* xw2 = H;                                  //   first N*128: xw2 (bf16)
  float* as2 = (float*)(H + (size_t)N * 128);               //   then N f32: alpha2_src
  float* ad2 = as2 + N;                                     //   then N f32: alpha2_dst
  float* as_   = (float*)(H + (size_t)N * 256);
  float* ad_   = as_ + N;
  int*   start_g = (int*)(ad_ + N);                         // N
  int*   deg_g   = start_g + N;                             // N
  int*   bkcnt   = deg_g + N;                               // 256
  unsigned* bpool = (unsigned*)(bkcnt + 256);               // NBUK*CAP u32
  unsigned short* csrc = (unsigned short*)(bpool + (size_t)NBUK * CAP);  // NBUK*CAP u16
  unsigned short* Wp1 = csrc + (size_t)NBUK * CAP;          // 128*256
  unsigned short* Wp2 = Wp1 + 128 * 256;                    // 256*128
  float* vecs  = (float*)(Wp2 + 256 * 128);                 // 1152 f32
  int*   flags = (int*)(vecs + 1152);
  float* w_as1 = vecs,        *w_ad1 = vecs + 128;          // W1 @ a1s/a1d (layer-1 trick)
  float* v_a2s = vecs + 256,  *v_a2d = vecs + 384;          // RAW a2s/a2d (layer-2 epilogue)
  float* v_b1  = vecs + 512,  *v_b2  = vecs + 768;

  const int NB = (N * 64 + 255) / 256;         // wave-per-node blocks
  const int BB = (EN + BIN_CH - 1) / BIN_CH;   // bin blocks
  const int AG = (N + 15) / 16;                // fused agg+gemm blocks (1024 thr)

  // ---- fused prep ----
  prep_k<<<260, 256, 0, stream>>>(x, ei, W1, a1s, a1d, b1, W2, a2s, a2d, b2,
                                  Wp1, Wp2, w_as1, w_ad1, v_a2s, v_a2d, v_b1, v_b2,
                                  bkcnt, flags);

  // ---- canon x -> bf16 + alpha1 ----
  canon_alpha_k<<<NB, 256, 0, stream>>>(x, w_as1, w_ad1, B1, as_, ad_, N, flags);

  // ---- bucketed CSR build ----
  bin_k<<<BB, 256, 0, stream>>>(ei, bpool, bkcnt, E, EN, N, flags);
  bucket_csr_k<<<NBUK, 256, 0, stream>>>(bpool, bkcnt, csrc, start_g, deg_g, N);

  // ===== layer 1+2 GEMMs fused: aggregate(x) + GEMM1 + relu + GEMM2 + alpha2 -> xw2 ====
  agg_gemm12_k<<<AG, 1024, 0, stream>>>(start_g, deg_g, csrc, as_, ad_, B1, Wp1, Wp2,
                                        v_b1, v_a2s, v_a2d, xw2, as2, ad2, N);

  // ===== final aggregate over xw2 =====
  agg_out_k<<<NB, 256, 0, stream>>>(start_g, deg_g, csrc, as2, ad2, xw2, v_b2, d_out, N, flags);
}